// Round 12
// baseline (141.901 us; speedup 1.0000x reference)
//
#include <hip/hip_runtime.h>

// Problem constants
#define BB 32
#define SS 512
#define DD 768
#define HH 12
#define HDIM 64
#define OL 256        // pooled query length
#define NQKV 2304     // 3*DD
#define GM (BB*SS)    // 16384 rows into the QKV GEMM

#define NEG2 (-14426.9504089f)   // -10000 * log2(e)

typedef __bf16 bf16_t;
typedef bf16_t bf16x8 __attribute__((ext_vector_type(8)));
typedef float f32x4 __attribute__((ext_vector_type(4)));
typedef unsigned short u16x8 __attribute__((ext_vector_type(8)));

__device__ __forceinline__ unsigned short f2bf(float f) {
  unsigned u = __float_as_uint(f);
  u = u + 0x7FFFu + ((u >> 16) & 1u);   // RNE
  return (unsigned short)(u >> 16);
}
__device__ __forceinline__ float b2f(unsigned short s) {
  return __uint_as_float(((unsigned)s) << 16);
}

// ---------------------------------------------------------------- conversions
__global__ void conv_f32_bf16(const float* __restrict__ in,
                              unsigned short* __restrict__ out, int n4) {
  int i = blockIdx.x * blockDim.x + threadIdx.x;
  if (i >= n4) return;
  float4 v = ((const float4*)in)[i];
  ushort4 o;
  o.x = f2bf(v.x); o.y = f2bf(v.y); o.z = f2bf(v.z); o.w = f2bf(v.w);
  ((ushort4*)out)[i] = o;
}

// ---------------------------------------------------------------- mask prep
// kbias pre-scaled by log2(e): 0 valid, -14427 masked.
__global__ void prep_mask(const void* __restrict__ mraw,
                          float* __restrict__ kbias,
                          float* __restrict__ invn,
                          unsigned char* __restrict__ nmask,
                          float* __restrict__ out_nm) {
  int b = blockIdx.x, t = threadIdx.x;
  const unsigned char* mb = (const unsigned char*)mraw;
  bool isbyte = (mb[1] != 0);
  int idx = b * SS + t;
  int mv = isbyte ? (int)(mb[idx] != 0) : (int)(((const int*)mraw)[idx] != 0);
  kbias[idx] = mv ? 0.f : NEG2;
  if (t < OL) {
    int i0 = b * SS + 2 * t, i1 = i0 + 1;
    int m0 = isbyte ? (int)(mb[i0] != 0) : (int)(((const int*)mraw)[i0] != 0);
    int m1 = isbyte ? (int)(mb[i1] != 0) : (int)(((const int*)mraw)[i1] != 0);
    int n = m0 + m1;
    invn[b * OL + t] = (n > 0) ? 1.f / (float)n : 1.f;
    nmask[b * OL + t] = (n > 0) ? 1 : 0;
    out_nm[b * OL + t] = (n > 0) ? 1.f : 0.f;   // second tuple output
  }
}

// ---------------------------------------------------------------- QKV GEMM
// 256x256 tile, BK=64, 8 waves (2M x 4N, per-wave 128x64 = 8x4 frags,
// 0.375 ds_read/MFMA), double-buffered LDS 128 KiB, R8-proven 2-cluster
// ledger: stage t+2 after barrier2, steady vmcnt(8), drain at last tile.
// T2 XOR-swizzle, T5 setprio, T1 XCD swizzle (576 = 8 x 72, m disjoint/XCD).
// Fused epilogues: n-tiles 0-2 -> pooled qp; 3-5 -> Kbuf; 6-8 -> vT.
__global__ __launch_bounds__(512, 2) void gemm_qkv(
    const unsigned short* __restrict__ A,
    const unsigned short* __restrict__ Bt,
    const float* __restrict__ bias,
    unsigned short* __restrict__ Kbuf,   // [B*S][768]
    unsigned short* __restrict__ qp,     // [B*OL][768]
    unsigned short* __restrict__ vT,     // [B][H][64][512]
    const float* __restrict__ kbias,
    const float* __restrict__ invn) {
  __shared__ __align__(16) char smem[131072];   // 2 x (A 32K + B 32K)

  const int t = threadIdx.x;
  const int lane = t & 63;
  const int w = t >> 6;          // 0..7
  const int wm = w >> 2;         // 0..1 (M: 128 rows each)
  const int wn = w & 3;          // 0..3 (N: 64 cols each)
  const int fr = lane & 15, hi = lane >> 4;

  // T1: 576 blocks = 8 XCDs x 72 (9 n-tiles fastest; m-tiles disjoint/XCD)
  const int p = blockIdx.x;
  const int l = (p & 7) * 72 + (p >> 3);
  const int m0 = (l / 9) * 256;
  const int n0 = (l % 9) * 256;
  const int b = m0 >> 9;
  const int s0 = m0 & 511;

  f32x4 acc[8][4] = {};

  const int sr8 = lane >> 3;
  const int sx8 = ((lane & 7) ^ sr8) * 8;       // pre-swizzled source col
  const int wq = __builtin_amdgcn_readfirstlane(w);
  const unsigned short* aS = A + (size_t)(m0 + wq * 32 + sr8) * DD + sx8;
  const unsigned short* bS = Bt + (size_t)(n0 + wq * 32 + sr8) * DD + sx8;

#define GLOAD(SRC, DST)                                                        \
  __builtin_amdgcn_global_load_lds(                                           \
      (const __attribute__((address_space(1))) unsigned int*)(SRC),           \
      (__attribute__((address_space(3))) unsigned int*)(DST), 16, 0, 0)

  // per K-tile: A 4 issues + B 4 issues per thread (8 total)
#define STAGE(KT, BUF) do {                                                    \
    char* da_ = (BUF);                                                         \
    char* db_ = (BUF) + 32768;                                                 \
    const unsigned short* as_ = aS + (KT) * 64;                                \
    const unsigned short* bs_ = bS + (KT) * 64;                                \
    _Pragma("unroll")                                                          \
    for (int q_ = 0; q_ < 4; ++q_) {                                           \
      GLOAD(as_ + (size_t)(8 * q_) * DD, da_ + (wq * 32 + 8 * q_) * 128);      \
      GLOAD(bs_ + (size_t)(8 * q_) * DD, db_ + (wq * 32 + 8 * q_) * 128);      \
    }                                                                          \
  } while (0)

#define MFMA32()                                                               \
  do {                                                                         \
    asm volatile("s_waitcnt lgkmcnt(0)" ::: "memory");                          \
    __builtin_amdgcn_sched_barrier(0);                                         \
    __builtin_amdgcn_s_setprio(1);                                             \
    _Pragma("unroll")                                                          \
    for (int mf_ = 0; mf_ < 8; ++mf_)                                          \
      _Pragma("unroll")                                                        \
      for (int nf_ = 0; nf_ < 4; ++nf_)                                        \
        acc[mf_][nf_] = __builtin_amdgcn_mfma_f32_16x16x32_bf16(               \
            af[mf_], bf[nf_], acc[mf_][nf_], 0, 0, 0);                         \
    __builtin_amdgcn_s_setprio(0);                                             \
  } while (0)

#define RD(SB, CB)                                                             \
  do {                                                                         \
    _Pragma("unroll")                                                          \
    for (int f_ = 0; f_ < 8; ++f_)                                             \
      af[f_] = *(const bf16x8*)((SB) + (wm * 128 + f_ * 16 + fr) * 128 + (CB)); \
    _Pragma("unroll")                                                          \
    for (int f_ = 0; f_ < 4; ++f_)                                             \
      bf[f_] = *(const bf16x8*)((SB) + 32768 + (wn * 64 + f_ * 16 + fr) * 128 + (CB)); \
  } while (0)

  const int cb0 = (hi * 16) ^ ((fr & 7) << 4);
  const int cb1 = (64 + hi * 16) ^ ((fr & 7) << 4);

  // prologue: tiles 0,1 -> bufs 0,1 (16 issues/thread outstanding)
  STAGE(0, smem);
  STAGE(1, smem + 65536);

#pragma unroll 2
  for (int kt = 0; kt < 12; ++kt) {
    if (kt < 11) {
      asm volatile("s_waitcnt vmcnt(8)" ::: "memory");   // tile kt landed
    } else {
      asm volatile("s_waitcnt vmcnt(0)" ::: "memory");
    }
    __builtin_amdgcn_sched_barrier(0);
    __builtin_amdgcn_s_barrier();
    __builtin_amdgcn_sched_barrier(0);

    char* bA = smem + (kt & 1) * 65536;
    bf16x8 af[8], bf[4];

    // ---- cluster 1: ks=0
    RD(bA, cb0);
    MFMA32();

    // ---- cluster 2: ks=1 (reads issued, buffer freed, stage, then MFMA)
    RD(bA, cb1);
    asm volatile("s_waitcnt lgkmcnt(0)" ::: "memory");
    __builtin_amdgcn_sched_barrier(0);
    __builtin_amdgcn_s_barrier();     // all waves done reading this buffer
    __builtin_amdgcn_sched_barrier(0);
    if (kt + 2 < 12) STAGE(kt + 2, bA);   // overwrite same parity — safe
    __builtin_amdgcn_sched_barrier(0);
    __builtin_amdgcn_s_setprio(1);
#pragma unroll
    for (int mf = 0; mf < 8; ++mf)
#pragma unroll
      for (int nf = 0; nf < 4; ++nf)
        acc[mf][nf] = __builtin_amdgcn_mfma_f32_16x16x32_bf16(
            af[mf], bf[nf], acc[mf][nf], 0, 0, 0);
    __builtin_amdgcn_s_setprio(0);
  }
#undef RD
#undef MFMA32
#undef STAGE
#undef GLOAD

  // ---------------- fused epilogues (per-wave output: 128 rows x 64 cols)
  const int nt = n0 / 768;   // 0=Q(pool), 1=K, 2=V(transpose)
  if (nt == 1) {
#pragma unroll
    for (int nf = 0; nf < 4; ++nf) {
      const int nc = wn * 64 + nf * 16 + fr;
      const float bvs = bias[n0 + nc];
      const int gnc = n0 - 768 + nc;
#pragma unroll
      for (int mf = 0; mf < 8; ++mf) {
        const int gmr = m0 + wm * 128 + mf * 16 + hi * 4;
#pragma unroll
        for (int j = 0; j < 4; ++j)
          Kbuf[(size_t)(gmr + j) * 768 + gnc] = f2bf(acc[mf][nf][j] + bvs);
      }
    }
  } else if (nt == 0) {
#pragma unroll
    for (int mf = 0; mf < 8; ++mf) {
      const int sl = s0 + wm * 128 + mf * 16 + hi * 4;   // seq of j=0
      const float4 km = *(const float4*)&kbias[b * SS + sl];
      const float2 iv = *(const float2*)&invn[b * OL + (sl >> 1)];
      const float w0 = (km.x == 0.f) ? iv.x : 0.f;
      const float w1 = (km.y == 0.f) ? iv.x : 0.f;
      const float w2 = (km.z == 0.f) ? iv.y : 0.f;
      const float w3 = (km.w == 0.f) ? iv.y : 0.f;
      const int o0 = b * OL + (sl >> 1);
#pragma unroll
      for (int nf = 0; nf < 4; ++nf) {
        const int gnc = n0 + wn * 64 + nf * 16 + fr;
        const float bvs = bias[gnc];
        const f32x4 a = acc[mf][nf];
        qp[(size_t)o0 * DD + gnc] = f2bf((a[0] + bvs) * w0 + (a[1] + bvs) * w1);
        qp[(size_t)(o0 + 1) * DD + gnc] = f2bf((a[2] + bvs) * w2 + (a[3] + bvs) * w3);
      }
    }
  } else {
    // V: per-wave transpose via LDS tile [64 d][72 s] ushort, two m-halves.
    // wave's cols = head h2, d = nf*16+fr; rows = 128 seq positions.
    const int h2 = ((n0 - 1536) >> 6) + wn;            // 0..11
    unsigned short* tile = (unsigned short*)(smem + wq * 9216);
    float bvs[4];
#pragma unroll
    for (int nf = 0; nf < 4; ++nf) bvs[nf] = bias[n0 + wn * 64 + nf * 16 + fr];
#pragma unroll
    for (int mh = 0; mh < 2; ++mh) {
#pragma unroll
      for (int nf = 0; nf < 4; ++nf) {
        const int d = nf * 16 + fr;
#pragma unroll
        for (int mf2 = 0; mf2 < 4; ++mf2) {
          const int mf = mh * 4 + mf2;
          ushort4 pk;
          pk.x = f2bf(acc[mf][nf][0] + bvs[nf]);
          pk.y = f2bf(acc[mf][nf][1] + bvs[nf]);
          pk.z = f2bf(acc[mf][nf][2] + bvs[nf]);
          pk.w = f2bf(acc[mf][nf][3] + bvs[nf]);
          *(ushort4*)&tile[d * 72 + mf2 * 16 + hi * 4] = pk;
        }
      }
      asm volatile("s_waitcnt lgkmcnt(0)" ::: "memory");
      __builtin_amdgcn_sched_barrier(0);
      const int sb = s0 + wm * 128 + mh * 64;
#pragma unroll
      for (int i = 0; i < 8; ++i) {
        const int task = i * 64 + lane;
        const int d = task >> 3, ch = task & 7;
        const u16x8 v = *(const u16x8*)&tile[d * 72 + ch * 8];
        *(u16x8*)(vT + ((size_t)((b * HH + h2) * HDIM + d)) * 512 + sb + ch * 8) = v;
      }
      asm volatile("s_waitcnt lgkmcnt(0)" ::: "memory");
      __builtin_amdgcn_sched_barrier(0);
    }
  }
}

// ---------------------------------------------------------------- attention
// slopes pre-scaled by log2(e)
__constant__ float c_slopes2[12] = {
    0.72134752f, 0.36067376f, 0.18033688f, 0.09016844f,
    0.04508422f, 0.02254211f, 0.011271055f, 0.0056355275f,
    1.02013945f, 0.51006972f, 0.25503486f, 0.12751743f};

// 4-wave block; block covers HALF the q-rows of one (b,h): wave w owns
// 32 q-rows (2 m-frags). 768 blocks x 4 waves = 3072 waves = 3/SIMD.
__global__ __launch_bounds__(256) void attn_mfma(
    const unsigned short* __restrict__ qp,    // [B][OL][768] bf16
    const unsigned short* __restrict__ Kb,    // [B*S][768] bf16
    const unsigned short* __restrict__ vT,    // [B][H][64][512] bf16
    const float* __restrict__ kbias,          // [B][S], pre-scaled log2e
    const unsigned char* __restrict__ nmask,  // [B][OL]
    float* __restrict__ out) {                // [B][OL][768]
  __shared__ __align__(16) char smem[51200];
  const int t = threadIdx.x;
  const int lane = t & 63;
  const int w = t >> 6;
  const int wq = __builtin_amdgcn_readfirstlane(w);
  const int fr = lane & 15, hi = lane >> 4;

  const int p = blockIdx.x;
  const int l = (p & 7) * 96 + (p >> 3);
  const int qb = l & 1;
  const int bh = l >> 1;
  const int h = bh % HH, b = bh / HH;
  const int q0 = qb * 128 + wq * 32;

  char* ptb = smem + 32768 + wq * 4096;
  float* kbl = (float*)(smem + 49152);

  const int srow = lane >> 3;
  const int scol = ((lane & 7) ^ srow) * 8;

#define GLOAD(SRC, DST)                                                        \
  __builtin_amdgcn_global_load_lds(                                           \
      (const __attribute__((address_space(1))) unsigned int*)(SRC),           \
      (__attribute__((address_space(3))) unsigned int*)(DST), 16, 0, 0)

  if (wq == 0) {
    GLOAD(kbias + b * SS + lane * 4, smem + 49152);
    GLOAD(kbias + b * SS + 256 + lane * 4, smem + 50176);
  }

  bf16x8 qf[2][2];
#pragma unroll
  for (int m = 0; m < 2; ++m)
#pragma unroll
    for (int ks = 0; ks < 2; ++ks)
      qf[m][ks] = *(const bf16x8*)(qp + (size_t)(b * OL + q0 + m * 16 + fr) * DD +
                                   h * HDIM + ks * 32 + hi * 8);

  int nmv = (int)nmask[b * OL + q0 + (lane & 31)];
  int qmbits = 0;
#pragma unroll
  for (int m = 0; m < 2; ++m)
#pragma unroll
    for (int j = 0; j < 4; ++j)
      if (__shfl(nmv, m * 16 + hi * 4 + j, 64)) qmbits |= 1 << (m * 4 + j);

  const float slope2 = c_slopes2[h];
  f32x4 oacc[2][4] = {};
  float lpart[2][4] = {};

#define STAGE(TILE, BUF) do {                                                  \
    char* kd_ = smem + (BUF) * 8192 + wq * 2048;                               \
    char* vd_ = smem + 16384 + (BUF) * 8192 + wq * 2048;                       \
    const unsigned short* ks_ =                                                \
        Kb + (size_t)(b * SS + (TILE) * 64 + wq * 16 + srow) * 768 + h * HDIM + scol; \
    const unsigned short* vs_ =                                                \
        vT + (size_t)((b * HH + h) * HDIM + wq * 16 + srow) * SS + (TILE) * 64 + scol; \
    GLOAD(ks_, kd_);                                                           \
    GLOAD(ks_ + (size_t)8 * 768, kd_ + 1024);                                  \
    GLOAD(vs_, vd_);                                                           \
    GLOAD(vs_ + (size_t)8 * SS, vd_ + 1024);                                   \
  } while (0)

  __builtin_amdgcn_sched_barrier(0);
  STAGE(0, 0);
  STAGE(1, 1);
  __builtin_amdgcn_sched_barrier(0);

  for (int tile = 0; tile < 8; ++tile) {
    const int cur = tile & 1;
    const int key0 = tile * 64;
    if (tile < 7) {
      asm volatile("s_waitcnt vmcnt(4)" ::: "memory");
    } else {
      asm volatile("s_waitcnt vmcnt(0)" ::: "memory");
    }
    __builtin_amdgcn_sched_barrier(0);
    __builtin_amdgcn_s_barrier();
    __builtin_amdgcn_sched_barrier(0);

    char* ktb = smem + cur * 8192;
    char* vtb = smem + 16384 + cur * 8192;

    // ---- QK^T
    f32x4 sacc[2][4] = {};
#pragma unroll
    for (int ks = 0; ks < 2; ++ks) {
      bf16x8 kf[4];
#pragma unroll
      for (int n = 0; n < 4; ++n) {
        const int by = ((n * 16 + fr) * 128 + (ks * 64 + hi * 16)) ^ ((fr & 7) << 4);
        kf[n] = *(const bf16x8*)(ktb + by);
      }
#pragma unroll
      for (int m = 0; m < 2; ++m)
#pragma unroll
        for (int n = 0; n < 4; ++n)
          sacc[m][n] = __builtin_amdgcn_mfma_f32_16x16x32_bf16(qf[m][ks], kf[n], sacc[m][n], 0, 0, 0);
    }

    // ---- fixed-max log2-domain softmax; P -> LDS (bf16)
    float kbv[4], keyfv[4];
#pragma unroll
    for (int n = 0; n < 4; ++n) {
      kbv[n] = kbl[key0 + n * 16 + fr];
      keyfv[n] = (float)(key0 + n * 16 + fr);
    }
#pragma unroll
    for (int m = 0; m < 2; ++m) {
#pragma unroll
      for (int j = 0; j < 4; ++j) {
        const bool qm = (qmbits >> (m * 4 + j)) & 1;
        const float qvf = (float)(q0 + m * 16 + hi * 4 + j);
        float lp = lpart[m][j];
#pragma unroll
        for (int n = 0; n < 4; ++n) {
          const float biasv = qm ? kbv[n] : 0.f;
          const float rel = fabsf(keyfv[n] - qvf);
          float tv = fmaf(sacc[m][n][j], 0.18033688011f, biasv);
          tv = fmaf(rel, -slope2, tv);
          float pe;
          asm("v_exp_f32 %0, %1" : "=v"(pe) : "v"(tv));
          lp += pe;
          const int by = ((m * 16 + hi * 4 + j) * 128 + (n * 16 + fr) * 2) ^
                         (((hi * 4 + j) & 7) << 4);
          *(unsigned short*)(ptb + by) = f2bf(pe);
        }
        lpart[m][j] = lp;
      }
    }
    asm volatile("s_waitcnt lgkmcnt(0)" ::: "memory");
    __builtin_amdgcn_sched_barrier(0);

    // ---- PV
#pragma unroll
    for (int ks = 0; ks < 2; ++ks) {
      bf16x8 pf[2], vf[4];
#pragma unroll
      for (int m = 0; m < 2; ++m) {
        const int by = ((m * 16 + fr) * 128 + (ks * 64 + hi * 16)) ^ ((fr & 7) << 4);
        pf[m] = *(const bf16x8*)(ptb + by);
      }
#pragma unroll
      for (int nd = 0; nd < 4; ++nd) {
        const int by = ((nd * 16 + fr) * 128 + (ks * 64 + hi * 16)) ^ ((fr & 7) << 4);
        vf[nd] = *(const bf16x8*)(vtb + by);
      }
#pragma unroll
      for (int m = 0; m < 2; ++m)
#pragma unroll
        for (int nd = 0; nd < 4; ++nd)
          oacc[m][nd] = __builtin_amdgcn_mfma_f32_16x16x32_bf16(pf[m], vf[nd], oacc[m][nd], 0, 0, 0);
    }

    __builtin_amdgcn_sched_barrier(0);
    __builtin_amdgcn_s_barrier();
    __builtin_amdgcn_sched_barrier(0);
    if (tile + 2 < 8) STAGE(tile + 2, cur);
  }
#undef STAGE
#undef GLOAD

  // ---- epilogue
  float* ot = (float*)(smem + wq * 8704);   // 32 x 68 f32
#pragma unroll
  for (int m = 0; m < 2; ++m)
#pragma unroll
    for (int j = 0; j < 4; ++j) {
      float lv = lpart[m][j];
      lv += __shfl_xor(lv, 1, 64);
      lv += __shfl_xor(lv, 2, 64);
      lv += __shfl_xor(lv, 4, 64);
      lv += __shfl_xor(lv, 8, 64);
      const float rl = 1.f / lv;
      const int row = m * 16 + hi * 4 + j;
#pragma unroll
      for (int nd = 0; nd < 4; ++nd)
        ot[row * 68 + nd * 16 + fr] = oacc[m][nd][j] * rl;
    }
  asm volatile("s_waitcnt lgkmcnt(0)" ::: "memory");
  __builtin_amdgcn_sched_barrier(0);
#pragma unroll
  for (int i = 0; i < 8; ++i) {
    const int idx = i * 64 + lane;
    const int row = idx >> 4, c4 = idx & 15;
    const float4 v = *(const float4*)&ot[row * 68 + c4 * 4];
    *(float4*)(out + (size_t)(b * OL + q0 + row) * DD + h * HDIM + c4 * 4) = v;
  }
}

// ---------------------------------------------------------------- launch
extern "C" void kernel_launch(void* const* d_in, const int* in_sizes, int n_in,
                              void* d_out, int out_size, void* d_ws, size_t ws_size,
                              hipStream_t stream) {
  const float* hidden = (const float*)d_in[0];
  const void* maskraw = d_in[1];
  const float* W = (const float*)d_in[2];
  const float* bias = (const float*)d_in[3];
  float* out = (float*)d_out;

  char* ws = (char*)d_ws;
  unsigned short* Abf  = (unsigned short*)(ws);                 // 25,165,824 B
  unsigned short* Btb  = (unsigned short*)(ws + 25165824);      //  3,538,944 B
  unsigned short* Kbuf = (unsigned short*)(ws + 28704768);      // 25,165,824 B
  unsigned short* vT   = (unsigned short*)(ws + 53870592);      // 25,165,824 B
  unsigned short* qp   = (unsigned short*)(ws + 79036416);      // 12,582,912 B
  float* kbias         = (float*)(ws + 91619328);               //     65,536 B
  float* invn          = (float*)(ws + 91684864);               //     32,768 B
  unsigned char* nmask = (unsigned char*)(ws + 91717632);       //      8,192 B

  float* out_nm = out + (size_t)BB * OL * DD;  // new_mask part of d_out

  conv_f32_bf16<<<(GM * DD / 4 + 255) / 256, 256, 0, stream>>>(hidden, Abf, GM * DD / 4);
  conv_f32_bf16<<<(NQKV * DD / 4 + 255) / 256, 256, 0, stream>>>(W, Btb, NQKV * DD / 4);
  prep_mask<<<BB, SS, 0, stream>>>(maskraw, kbias, invn, nmask, out_nm);
  gemm_qkv<<<576, 512, 0, stream>>>(Abf, Btb, bias, Kbuf, qp, vT, kbias, invn);
  attn_mfma<<<768, 256, 0, stream>>>(qp, Kbuf, vT, kbias, nmask, out);
}

// Round 13
// 107.308 us; speedup vs baseline: 1.3224x; 1.3224x over previous
//
#include <hip/hip_runtime.h>

// Problem constants
#define BB 32
#define SS 512
#define DD 768
#define HH 12
#define HDIM 64
#define OL 256        // pooled query length
#define NQKV 2304     // 3*DD
#define GM (BB*SS)    // 16384 rows into the QKV GEMM

#define NEG2 (-14426.9504089f)   // -10000 * log2(e)

typedef __bf16 bf16_t;
typedef bf16_t bf16x8 __attribute__((ext_vector_type(8)));
typedef float f32x4 __attribute__((ext_vector_type(4)));
typedef unsigned short u16x8 __attribute__((ext_vector_type(8)));

__device__ __forceinline__ unsigned short f2bf(float f) {
  unsigned u = __float_as_uint(f);
  u = u + 0x7FFFu + ((u >> 16) & 1u);   // RNE
  return (unsigned short)(u >> 16);
}
__device__ __forceinline__ float b2f(unsigned short s) {
  return __uint_as_float(((unsigned)s) << 16);
}

// ---------------------------------------------------------------- conversions
__global__ void conv_f32_bf16(const float* __restrict__ in,
                              unsigned short* __restrict__ out, int n4) {
  int i = blockIdx.x * blockDim.x + threadIdx.x;
  if (i >= n4) return;
  float4 v = ((const float4*)in)[i];
  ushort4 o;
  o.x = f2bf(v.x); o.y = f2bf(v.y); o.z = f2bf(v.z); o.w = f2bf(v.w);
  ((ushort4*)out)[i] = o;
}

// ---------------------------------------------------------------- mask prep
// kbias pre-scaled by log2(e): 0 valid, -14427 masked.
__global__ void prep_mask(const void* __restrict__ mraw,
                          float* __restrict__ kbias,
                          float* __restrict__ invn,
                          unsigned char* __restrict__ nmask,
                          float* __restrict__ out_nm) {
  int b = blockIdx.x, t = threadIdx.x;
  const unsigned char* mb = (const unsigned char*)mraw;
  bool isbyte = (mb[1] != 0);
  int idx = b * SS + t;
  int mv = isbyte ? (int)(mb[idx] != 0) : (int)(((const int*)mraw)[idx] != 0);
  kbias[idx] = mv ? 0.f : NEG2;
  if (t < OL) {
    int i0 = b * SS + 2 * t, i1 = i0 + 1;
    int m0 = isbyte ? (int)(mb[i0] != 0) : (int)(((const int*)mraw)[i0] != 0);
    int m1 = isbyte ? (int)(mb[i1] != 0) : (int)(((const int*)mraw)[i1] != 0);
    int n = m0 + m1;
    invn[b * OL + t] = (n > 0) ? 1.f / (float)n : 1.f;
    nmask[b * OL + t] = (n > 0) ? 1 : 0;
    out_nm[b * OL + t] = (n > 0) ? 1.f : 0.f;   // second tuple output
  }
}

// ---------------------------------------------------------------- A conv+pool
// Emits full bf16 A (for K/V GEMM) and mask-weighted pooled bf16 A (for the
// Q GEMM): Apool[b,o] = (h[2o]*m(2o) + h[2o+1]*m(2o+1)) * invn.
__global__ void pool_conv(const float* __restrict__ hidden,
                          const float* __restrict__ kbias,
                          const float* __restrict__ invn,
                          unsigned short* __restrict__ Abf,
                          unsigned short* __restrict__ Apool) {
  int i = blockIdx.x * blockDim.x + threadIdx.x;
  if (i >= BB * OL * (DD / 4)) return;
  const int c = (i % 192) * 4;
  const int ol = i / 192;
  const int b = ol >> 8, o = ol & 255;
  const int s0 = b * SS + 2 * o;
  const float4 h0 = *(const float4*)(hidden + (size_t)s0 * DD + c);
  const float4 h1 = *(const float4*)(hidden + (size_t)(s0 + 1) * DD + c);
  ushort4 a0, a1, ap;
  a0.x = f2bf(h0.x); a0.y = f2bf(h0.y); a0.z = f2bf(h0.z); a0.w = f2bf(h0.w);
  a1.x = f2bf(h1.x); a1.y = f2bf(h1.y); a1.z = f2bf(h1.z); a1.w = f2bf(h1.w);
  const float m0v = (kbias[s0] == 0.f) ? 1.f : 0.f;
  const float m1v = (kbias[s0 + 1] == 0.f) ? 1.f : 0.f;
  const float inv = invn[ol];
  ap.x = f2bf((h0.x * m0v + h1.x * m1v) * inv);
  ap.y = f2bf((h0.y * m0v + h1.y * m1v) * inv);
  ap.z = f2bf((h0.z * m0v + h1.z * m1v) * inv);
  ap.w = f2bf((h0.w * m0v + h1.w * m1v) * inv);
  *(ushort4*)(Abf + (size_t)s0 * DD + c) = a0;
  *(ushort4*)(Abf + (size_t)(s0 + 1) * DD + c) = a1;
  *(ushort4*)(Apool + (size_t)ol * DD + c) = ap;
}

// ---------------------------------------------------------------- QKV GEMM
// R8-proven structure: 128x128 tile, BK=64, 4 waves (2M x 2N), dbuf 64 KiB
// -> 2 blocks/CU, counted vmcnt(8), T2 XOR-swizzle, T5 setprio.
// Grid 1920 = 8 XCDs x 240: l<1536 -> K/V over full M=16384 (n0=768+...);
// l>=1536 -> Q over POOLED M=8192 (A=Apool, n0=0..767).
// Epilogues: Q -> qp (nmask gate), K -> Kbuf, V -> vT (LDS transpose).
#define NT 12   // 768 / 64
__global__ __launch_bounds__(256, 2) void gemm_qkv(
    const unsigned short* __restrict__ A,      // [16384][768]
    const unsigned short* __restrict__ Apool,  // [8192][768]
    const unsigned short* __restrict__ Bt,     // [2304][768]
    const float* __restrict__ bias,
    unsigned short* __restrict__ Kbuf,   // [B*S][768]
    unsigned short* __restrict__ qp,     // [B*OL][768]
    unsigned short* __restrict__ vT,     // [B][H][64][512]
    const unsigned char* __restrict__ nmask) {
  __shared__ __align__(16) char smem[65536];  // 2 x (A 16K + B 16K)

  const int t = threadIdx.x;
  const int lane = t & 63;
  const int w = t >> 6;          // 0..3
  const int wm = w >> 1, wn = w & 1;
  const int fr = lane & 15, hi = lane >> 4;

  // T1: bijective XCD-chunk swizzle; 1920 blocks = 8 XCDs x 240
  const int p = blockIdx.x;
  const int l = (p & 7) * 240 + (p >> 3);
  const bool isQ = l >= 1536;
  int m0, n0;
  if (!isQ) { m0 = (l / 12) * 128; n0 = 768 + (l % 12) * 128; }
  else      { const int l2 = l - 1536; m0 = (l2 / 6) * 128; n0 = (l2 % 6) * 128; }
  const unsigned short* Asel = isQ ? Apool : A;

  f32x4 acc[4][4] = {};

  const int sr8 = lane >> 3;                      // 0..7
  const int sx8 = ((lane & 7) ^ sr8) * 8;         // pre-swizzled src col
  const int wq = __builtin_amdgcn_readfirstlane(w);
  const unsigned short* aSrc = Asel + (size_t)(m0 + wq * 32 + sr8) * DD + sx8;
  const unsigned short* bSrc = Bt + (size_t)(n0 + wq * 32 + sr8) * DD + sx8;

#define GLOAD(SRC, DST)                                                        \
  __builtin_amdgcn_global_load_lds(                                           \
      (const __attribute__((address_space(1))) unsigned int*)(SRC),           \
      (__attribute__((address_space(3))) unsigned int*)(DST), 16, 0, 0)

  // 8 loads per wave per tile: 4 A-row-chunks + 4 B-row-chunks
#define STAGE(T) do {                                                          \
    char* da_ = smem + ((T) & 1) * 32768;                                      \
    char* db_ = da_ + 16384;                                                   \
    const unsigned short* as_ = aSrc + (T) * 64;                               \
    const unsigned short* bs_ = bSrc + (T) * 64;                               \
    _Pragma("unroll")                                                          \
    for (int i_ = 0; i_ < 4; ++i_) {                                           \
      GLOAD(as_ + (size_t)i_ * 8 * DD, da_ + (wq * 32 + i_ * 8) * 128);        \
      GLOAD(bs_ + (size_t)i_ * 8 * DD, db_ + (wq * 32 + i_ * 8) * 128);        \
    }                                                                          \
  } while (0)

  STAGE(0);
  STAGE(1);

  const int cb0 = (hi * 16) ^ ((fr & 7) << 4);
  const int cb1 = (64 + hi * 16) ^ ((fr & 7) << 4);

  for (int kt = 0; kt < NT; ++kt) {
    if (kt < NT - 1) {
      asm volatile("s_waitcnt vmcnt(8)" ::: "memory");
    } else {
      asm volatile("s_waitcnt vmcnt(0)" ::: "memory");
    }
    __builtin_amdgcn_sched_barrier(0);
    __builtin_amdgcn_s_barrier();
    __builtin_amdgcn_sched_barrier(0);

    const char* bA = smem + (kt & 1) * 32768;
    const char* bB = bA + 16384;

    bf16x8 a0[4], b0[4], a1[4], b1[4];
#pragma unroll
    for (int f = 0; f < 4; ++f) {
      a0[f] = *(const bf16x8*)(bA + (wm * 64 + f * 16 + fr) * 128 + cb0);
      b0[f] = *(const bf16x8*)(bB + (wn * 64 + f * 16 + fr) * 128 + cb0);
    }
    __builtin_amdgcn_sched_barrier(0);
#pragma unroll
    for (int f = 0; f < 4; ++f) {
      a1[f] = *(const bf16x8*)(bA + (wm * 64 + f * 16 + fr) * 128 + cb1);
      b1[f] = *(const bf16x8*)(bB + (wn * 64 + f * 16 + fr) * 128 + cb1);
    }
    asm volatile("s_waitcnt lgkmcnt(8)" ::: "memory");
    __builtin_amdgcn_sched_barrier(0);
    __builtin_amdgcn_s_setprio(1);
#pragma unroll
    for (int mf = 0; mf < 4; ++mf)
#pragma unroll
      for (int nf = 0; nf < 4; ++nf)
        acc[mf][nf] = __builtin_amdgcn_mfma_f32_16x16x32_bf16(
            a0[mf], b0[nf], acc[mf][nf], 0, 0, 0);
    __builtin_amdgcn_s_setprio(0);
    asm volatile("s_waitcnt lgkmcnt(0)" ::: "memory");
    __builtin_amdgcn_sched_barrier(0);
    __builtin_amdgcn_s_barrier();     // all waves done reading this buffer
    __builtin_amdgcn_sched_barrier(0);
    if (kt + 2 < NT) STAGE(kt + 2);   // writes this parity — now safe
    __builtin_amdgcn_sched_barrier(0);
    __builtin_amdgcn_s_setprio(1);
#pragma unroll
    for (int mf = 0; mf < 4; ++mf)
#pragma unroll
      for (int nf = 0; nf < 4; ++nf)
        acc[mf][nf] = __builtin_amdgcn_mfma_f32_16x16x32_bf16(
            a1[mf], b1[nf], acc[mf][nf], 0, 0, 0);
    __builtin_amdgcn_s_setprio(0);
  }
#undef STAGE
#undef GLOAD

  // ---------------- fused epilogues
  if (isQ) {
    // pooled-Q: qp = (Apool@Wq + bias) * nmask
#pragma unroll
    for (int mf = 0; mf < 4; ++mf) {
      const int r0 = m0 + wm * 64 + mf * 16 + hi * 4;   // pooled row of j=0
      const uchar4 nm = *(const uchar4*)&nmask[r0];
      const float g0 = nm.x ? 1.f : 0.f;
      const float g1 = nm.y ? 1.f : 0.f;
      const float g2 = nm.z ? 1.f : 0.f;
      const float g3 = nm.w ? 1.f : 0.f;
#pragma unroll
      for (int nf = 0; nf < 4; ++nf) {
        const int gnc = n0 + wn * 64 + nf * 16 + fr;    // 0..767
        const float bvs = bias[gnc];
        const f32x4 a = acc[mf][nf];
        qp[(size_t)(r0 + 0) * 768 + gnc] = f2bf((a[0] + bvs) * g0);
        qp[(size_t)(r0 + 1) * 768 + gnc] = f2bf((a[1] + bvs) * g1);
        qp[(size_t)(r0 + 2) * 768 + gnc] = f2bf((a[2] + bvs) * g2);
        qp[(size_t)(r0 + 3) * 768 + gnc] = f2bf((a[3] + bvs) * g3);
      }
    }
  } else if (n0 < 1536) {
    // K
#pragma unroll
    for (int nf = 0; nf < 4; ++nf) {
      const int nc = wn * 64 + nf * 16 + fr;
      const float bvs = bias[n0 + nc];
      const int gnc = n0 - 768 + nc;
#pragma unroll
      for (int mf = 0; mf < 4; ++mf) {
        const int gmr = m0 + wm * 64 + mf * 16 + hi * 4;
#pragma unroll
        for (int j = 0; j < 4; ++j)
          Kbuf[(size_t)(gmr + j) * 768 + gnc] = f2bf(acc[mf][nf][j] + bvs);
      }
    }
  } else {
    // V: bias + bf16 into LDS [128 n][136 m], then transposed coalesced store
    const int b = m0 >> 9;
    const int s0 = m0 & 511;
    unsigned short* lt = (unsigned short*)smem;
#pragma unroll
    for (int nf = 0; nf < 4; ++nf) {
      const int nl = wn * 64 + nf * 16 + fr;
      const float bvs = bias[n0 + nl];
#pragma unroll
      for (int mf = 0; mf < 4; ++mf) {
        const int mb = wm * 64 + mf * 16 + hi * 4;
        ushort4 pk;
        pk.x = f2bf(acc[mf][nf][0] + bvs);
        pk.y = f2bf(acc[mf][nf][1] + bvs);
        pk.z = f2bf(acc[mf][nf][2] + bvs);
        pk.w = f2bf(acc[mf][nf][3] + bvs);
        *(ushort4*)&lt[nl * 136 + mb] = pk;
      }
    }
    __syncthreads();
#pragma unroll
    for (int i = 0; i < 8; ++i) {
      const int row = i * 16 + (t >> 4);
      const int ch = t & 15;
      const u16x8 v = *(const u16x8*)&lt[row * 136 + ch * 8];
      const int n = n0 - 1536 + row;
      const int h2 = n >> 6, d2 = n & 63;
      *(u16x8*)(vT + ((size_t)((b * HH + h2) * HDIM + d2)) * 512 + s0 + ch * 8) = v;
    }
  }
}

// ---------------------------------------------------------------- attention
// slopes pre-scaled by log2(e)
__constant__ float c_slopes2[12] = {
    0.72134752f, 0.36067376f, 0.18033688f, 0.09016844f,
    0.04508422f, 0.02254211f, 0.011271055f, 0.0056355275f,
    1.02013945f, 0.51006972f, 0.25503486f, 0.12751743f};

// 4-wave block; block covers HALF the q-rows of one (b,h): wave w owns
// 32 q-rows (2 m-frags). 768 blocks x 4 waves = 3072 waves = 3/SIMD.
__global__ __launch_bounds__(256) void attn_mfma(
    const unsigned short* __restrict__ qp,    // [B][OL][768] bf16
    const unsigned short* __restrict__ Kb,    // [B*S][768] bf16
    const unsigned short* __restrict__ vT,    // [B][H][64][512] bf16
    const float* __restrict__ kbias,          // [B][S], pre-scaled log2e
    const unsigned char* __restrict__ nmask,  // [B][OL]
    float* __restrict__ out) {                // [B][OL][768]
  __shared__ __align__(16) char smem[51200];
  const int t = threadIdx.x;
  const int lane = t & 63;
  const int w = t >> 6;
  const int wq = __builtin_amdgcn_readfirstlane(w);
  const int fr = lane & 15, hi = lane >> 4;

  const int p = blockIdx.x;
  const int l = (p & 7) * 96 + (p >> 3);
  const int qb = l & 1;
  const int bh = l >> 1;
  const int h = bh % HH, b = bh / HH;
  const int q0 = qb * 128 + wq * 32;

  char* ptb = smem + 32768 + wq * 4096;
  float* kbl = (float*)(smem + 49152);

  const int srow = lane >> 3;
  const int scol = ((lane & 7) ^ srow) * 8;

#define GLOAD(SRC, DST)                                                        \
  __builtin_amdgcn_global_load_lds(                                           \
      (const __attribute__((address_space(1))) unsigned int*)(SRC),           \
      (__attribute__((address_space(3))) unsigned int*)(DST), 16, 0, 0)

  if (wq == 0) {
    GLOAD(kbias + b * SS + lane * 4, smem + 49152);
    GLOAD(kbias + b * SS + 256 + lane * 4, smem + 50176);
  }

  bf16x8 qf[2][2];
#pragma unroll
  for (int m = 0; m < 2; ++m)
#pragma unroll
    for (int ks = 0; ks < 2; ++ks)
      qf[m][ks] = *(const bf16x8*)(qp + (size_t)(b * OL + q0 + m * 16 + fr) * DD +
                                   h * HDIM + ks * 32 + hi * 8);

  int nmv = (int)nmask[b * OL + q0 + (lane & 31)];
  int qmbits = 0;
#pragma unroll
  for (int m = 0; m < 2; ++m)
#pragma unroll
    for (int j = 0; j < 4; ++j)
      if (__shfl(nmv, m * 16 + hi * 4 + j, 64)) qmbits |= 1 << (m * 4 + j);

  const float slope2 = c_slopes2[h];
  f32x4 oacc[2][4] = {};
  float lpart[2][4] = {};

#define STAGE(TILE, BUF) do {                                                  \
    char* kd_ = smem + (BUF) * 8192 + wq * 2048;                               \
    char* vd_ = smem + 16384 + (BUF) * 8192 + wq * 2048;                       \
    const unsigned short* ks_ =                                                \
        Kb + (size_t)(b * SS + (TILE) * 64 + wq * 16 + srow) * 768 + h * HDIM + scol; \
    const unsigned short* vs_ =                                                \
        vT + (size_t)((b * HH + h) * HDIM + wq * 16 + srow) * SS + (TILE) * 64 + scol; \
    GLOAD(ks_, kd_);                                                           \
    GLOAD(ks_ + (size_t)8 * 768, kd_ + 1024);                                  \
    GLOAD(vs_, vd_);                                                           \
    GLOAD(vs_ + (size_t)8 * SS, vd_ + 1024);                                   \
  } while (0)

  __builtin_amdgcn_sched_barrier(0);
  STAGE(0, 0);
  STAGE(1, 1);
  __builtin_amdgcn_sched_barrier(0);

  for (int tile = 0; tile < 8; ++tile) {
    const int cur = tile & 1;
    const int key0 = tile * 64;
    if (tile < 7) {
      asm volatile("s_waitcnt vmcnt(4)" ::: "memory");
    } else {
      asm volatile("s_waitcnt vmcnt(0)" ::: "memory");
    }
    __builtin_amdgcn_sched_barrier(0);
    __builtin_amdgcn_s_barrier();
    __builtin_amdgcn_sched_barrier(0);

    char* ktb = smem + cur * 8192;
    char* vtb = smem + 16384 + cur * 8192;

    // ---- QK^T
    f32x4 sacc[2][4] = {};
#pragma unroll
    for (int ks = 0; ks < 2; ++ks) {
      bf16x8 kf[4];
#pragma unroll
      for (int n = 0; n < 4; ++n) {
        const int by = ((n * 16 + fr) * 128 + (ks * 64 + hi * 16)) ^ ((fr & 7) << 4);
        kf[n] = *(const bf16x8*)(ktb + by);
      }
#pragma unroll
      for (int m = 0; m < 2; ++m)
#pragma unroll
        for (int n = 0; n < 4; ++n)
          sacc[m][n] = __builtin_amdgcn_mfma_f32_16x16x32_bf16(qf[m][ks], kf[n], sacc[m][n], 0, 0, 0);
    }

    // ---- fixed-max log2-domain softmax; P -> LDS (bf16)
    float kbv[4], keyfv[4];
#pragma unroll
    for (int n = 0; n < 4; ++n) {
      kbv[n] = kbl[key0 + n * 16 + fr];
      keyfv[n] = (float)(key0 + n * 16 + fr);
    }
#pragma unroll
    for (int m = 0; m < 2; ++m) {
#pragma unroll
      for (int j = 0; j < 4; ++j) {
        const bool qm = (qmbits >> (m * 4 + j)) & 1;
        const float qvf = (float)(q0 + m * 16 + hi * 4 + j);
        float lp = lpart[m][j];
#pragma unroll
        for (int n = 0; n < 4; ++n) {
          const float biasv = qm ? kbv[n] : 0.f;
          const float rel = fabsf(keyfv[n] - qvf);
          float tv = fmaf(sacc[m][n][j], 0.18033688011f, biasv);
          tv = fmaf(rel, -slope2, tv);
          float pe;
          asm("v_exp_f32 %0, %1" : "=v"(pe) : "v"(tv));
          lp += pe;
          const int by = ((m * 16 + hi * 4 + j) * 128 + (n * 16 + fr) * 2) ^
                         (((hi * 4 + j) & 7) << 4);
          *(unsigned short*)(ptb + by) = f2bf(pe);
        }
        lpart[m][j] = lp;
      }
    }
    asm volatile("s_waitcnt lgkmcnt(0)" ::: "memory");
    __builtin_amdgcn_sched_barrier(0);

    // ---- PV
#pragma unroll
    for (int ks = 0; ks < 2; ++ks) {
      bf16x8 pf[2], vf[4];
#pragma unroll
      for (int m = 0; m < 2; ++m) {
        const int by = ((m * 16 + fr) * 128 + (ks * 64 + hi * 16)) ^ ((fr & 7) << 4);
        pf[m] = *(const bf16x8*)(ptb + by);
      }
#pragma unroll
      for (int nd = 0; nd < 4; ++nd) {
        const int by = ((nd * 16 + fr) * 128 + (ks * 64 + hi * 16)) ^ ((fr & 7) << 4);
        vf[nd] = *(const bf16x8*)(vtb + by);
      }
#pragma unroll
      for (int m = 0; m < 2; ++m)
#pragma unroll
        for (int nd = 0; nd < 4; ++nd)
          oacc[m][nd] = __builtin_amdgcn_mfma_f32_16x16x32_bf16(pf[m], vf[nd], oacc[m][nd], 0, 0, 0);
    }

    __builtin_amdgcn_sched_barrier(0);
    __builtin_amdgcn_s_barrier();
    __builtin_amdgcn_sched_barrier(0);
    if (tile + 2 < 8) STAGE(tile + 2, cur);
  }
#undef STAGE
#undef GLOAD

  // ---- epilogue
  float* ot = (float*)(smem + wq * 8704);   // 32 x 68 f32
#pragma unroll
  for (int m = 0; m < 2; ++m)
#pragma unroll
    for (int j = 0; j < 4; ++j) {
      float lv = lpart[m][j];
      lv += __shfl_xor(lv, 1, 64);
      lv += __shfl_xor(lv, 2, 64);
      lv += __shfl_xor(lv, 4, 64);
      lv += __shfl_xor(lv, 8, 64);
      const float rl = 1.f / lv;
      const int row = m * 16 + hi * 4 + j;
#pragma unroll
      for (int nd = 0; nd < 4; ++nd)
        ot[row * 68 + nd * 16 + fr] = oacc[m][nd][j] * rl;
    }
  asm volatile("s_waitcnt lgkmcnt(0)" ::: "memory");
  __builtin_amdgcn_sched_barrier(0);
#pragma unroll
  for (int i = 0; i < 8; ++i) {
    const int idx = i * 64 + lane;
    const int row = idx >> 4, c4 = idx & 15;
    const float4 v = *(const float4*)&ot[row * 68 + c4 * 4];
    *(float4*)(out + (size_t)(b * OL + q0 + row) * DD + h * HDIM + c4 * 4) = v;
  }
}

// ---------------------------------------------------------------- launch
extern "C" void kernel_launch(void* const* d_in, const int* in_sizes, int n_in,
                              void* d_out, int out_size, void* d_ws, size_t ws_size,
                              hipStream_t stream) {
  const float* hidden = (const float*)d_in[0];
  const void* maskraw = d_in[1];
  const float* W = (const float*)d_in[2];
  const float* bias = (const float*)d_in[3];
  float* out = (float*)d_out;

  char* ws = (char*)d_ws;
  unsigned short* Abf   = (unsigned short*)(ws);                 // 25,165,824 B
  unsigned short* Btb   = (unsigned short*)(ws + 25165824);      //  3,538,944 B
  unsigned short* Kbuf  = (unsigned short*)(ws + 28704768);      // 25,165,824 B
  unsigned short* vT    = (unsigned short*)(ws + 53870592);      // 25,165,824 B
  unsigned short* qp    = (unsigned short*)(ws + 79036416);      // 12,582,912 B
  float* kbias          = (float*)(ws + 91619328);               //     65,536 B
  float* invn           = (float*)(ws + 91684864);               //     32,768 B
  unsigned char* nmask  = (unsigned char*)(ws + 91717632);       //      8,192 B
  unsigned short* Apool = (unsigned short*)(ws + 91725824);      // 12,582,912 B

  float* out_nm = out + (size_t)BB * OL * DD;  // new_mask part of d_out

  conv_f32_bf16<<<(NQKV * DD / 4 + 255) / 256, 256, 0, stream>>>(W, Btb, NQKV * DD / 4);
  prep_mask<<<BB, SS, 0, stream>>>(maskraw, kbias, invn, nmask, out_nm);
  pool_conv<<<(BB * OL * (DD / 4) + 255) / 256, 256, 0, stream>>>(hidden, kbias, invn, Abf, Apool);
  gemm_qkv<<<1920, 256, 0, stream>>>(Abf, Apool, Btb, bias, Kbuf, qp, vT, nmask);
  attn_mfma<<<768, 256, 0, stream>>>(qp, Kbuf, vT, kbias, nmask, out);
}

// Round 14
// 96.587 us; speedup vs baseline: 1.4692x; 1.1110x over previous
//
#include <hip/hip_runtime.h>

// Problem constants
#define BB 32
#define SS 512
#define DD 768
#define HH 12
#define HDIM 64
#define OL 256        // pooled query length
#define NQKV 2304     // 3*DD
#define GM (BB*SS)    // 16384 rows into the QKV GEMM

#define NEG2 (-14426.9504089f)   // -10000 * log2(e)

typedef __bf16 bf16_t;
typedef bf16_t bf16x8 __attribute__((ext_vector_type(8)));
typedef float f32x4 __attribute__((ext_vector_type(4)));
typedef unsigned short u16x8 __attribute__((ext_vector_type(8)));

__device__ __forceinline__ unsigned short f2bf(float f) {
  unsigned u = __float_as_uint(f);
  u = u + 0x7FFFu + ((u >> 16) & 1u);   // RNE
  return (unsigned short)(u >> 16);
}
__device__ __forceinline__ float b2f(unsigned short s) {
  return __uint_as_float(((unsigned)s) << 16);
}

// ---------------------------------------------------------------- fused prep
// blocks [0,1728): W f32->bf16
// blocks [1728,1792): mask -> kbias/invn/nmask/out_nm
// blocks [1792,7936): hidden -> Abf (bf16) + Apool (mask-weighted pooled bf16)
__global__ __launch_bounds__(256) void prep_all(
    const float* __restrict__ hidden,
    const void* __restrict__ mraw,
    const float* __restrict__ W,
    unsigned short* __restrict__ Btb,
    unsigned short* __restrict__ Abf,
    unsigned short* __restrict__ Apool,
    float* __restrict__ kbias,
    float* __restrict__ invn,
    unsigned char* __restrict__ nmask,
    float* __restrict__ out_nm) {
  const int blk = blockIdx.x;
  const int t = threadIdx.x;
  const unsigned char* mb = (const unsigned char*)mraw;

  if (blk < 1728) {
    // ---- W conversion (442368 float4 items)
    const int i = blk * 256 + t;
    float4 v = ((const float4*)W)[i];
    ushort4 o;
    o.x = f2bf(v.x); o.y = f2bf(v.y); o.z = f2bf(v.z); o.w = f2bf(v.w);
    ((ushort4*)Btb)[i] = o;
  } else if (blk < 1792) {
    // ---- mask prep (16384 positions)
    const int idx = (blk - 1728) * 256 + t;
    const int b = idx >> 9, s = idx & 511;
    const bool isbyte = (mb[1] != 0);
    const int mv = isbyte ? (int)(mb[idx] != 0) : (int)(((const int*)mraw)[idx] != 0);
    kbias[idx] = mv ? 0.f : NEG2;
    if (s < OL) {
      const int i0 = b * SS + 2 * s, i1 = i0 + 1;
      const int m0 = isbyte ? (int)(mb[i0] != 0) : (int)(((const int*)mraw)[i0] != 0);
      const int m1 = isbyte ? (int)(mb[i1] != 0) : (int)(((const int*)mraw)[i1] != 0);
      const int n = m0 + m1;
      invn[b * OL + s] = (n > 0) ? 1.f / (float)n : 1.f;
      nmask[b * OL + s] = (n > 0) ? 1 : 0;
      out_nm[b * OL + s] = (n > 0) ? 1.f : 0.f;
    }
  } else {
    // ---- hidden conversion + pooling (1572864 items; reads mask directly)
    const int i = (blk - 1792) * 256 + t;
    const int c = (i % 192) * 4;
    const int ol = i / 192;
    const int b = ol >> 8, o = ol & 255;
    const int s0 = b * SS + 2 * o;
    const bool isbyte = (mb[1] != 0);
    const int m0 = isbyte ? (int)(mb[s0] != 0) : (int)(((const int*)mraw)[s0] != 0);
    const int m1 = isbyte ? (int)(mb[s0 + 1] != 0) : (int)(((const int*)mraw)[s0 + 1] != 0);
    const int n = m0 + m1;
    const float inv = (n > 0) ? 1.f / (float)n : 1.f;
    const float m0v = (float)m0, m1v = (float)m1;
    const float4 h0 = *(const float4*)(hidden + (size_t)s0 * DD + c);
    const float4 h1 = *(const float4*)(hidden + (size_t)(s0 + 1) * DD + c);
    ushort4 a0, a1, ap;
    a0.x = f2bf(h0.x); a0.y = f2bf(h0.y); a0.z = f2bf(h0.z); a0.w = f2bf(h0.w);
    a1.x = f2bf(h1.x); a1.y = f2bf(h1.y); a1.z = f2bf(h1.z); a1.w = f2bf(h1.w);
    ap.x = f2bf((h0.x * m0v + h1.x * m1v) * inv);
    ap.y = f2bf((h0.y * m0v + h1.y * m1v) * inv);
    ap.z = f2bf((h0.z * m0v + h1.z * m1v) * inv);
    ap.w = f2bf((h0.w * m0v + h1.w * m1v) * inv);
    *(ushort4*)(Abf + (size_t)s0 * DD + c) = a0;
    *(ushort4*)(Abf + (size_t)(s0 + 1) * DD + c) = a1;
    *(ushort4*)(Apool + (size_t)ol * DD + c) = ap;
  }
}

// ---------------------------------------------------------------- QKV GEMM
// R8-proven structure: 128x128 tile, BK=64, 4 waves (2M x 2N), dbuf 64 KiB
// -> 2 blocks/CU, counted vmcnt(8), T2 XOR-swizzle, T5 setprio.
// Grid 1920 = 8 XCDs x 240: l<1536 -> K/V over full M=16384 (n0=768+...);
// l>=1536 -> Q over POOLED M=8192 (A=Apool, n0=0..767).
#define NT 12   // 768 / 64
__global__ __launch_bounds__(256, 2) void gemm_qkv(
    const unsigned short* __restrict__ A,      // [16384][768]
    const unsigned short* __restrict__ Apool,  // [8192][768]
    const unsigned short* __restrict__ Bt,     // [2304][768]
    const float* __restrict__ bias,
    unsigned short* __restrict__ Kbuf,   // [B*S][768]
    unsigned short* __restrict__ qp,     // [B*OL][768]
    unsigned short* __restrict__ vT,     // [B][H][64][512]
    const unsigned char* __restrict__ nmask) {
  __shared__ __align__(16) char smem[65536];  // 2 x (A 16K + B 16K)

  const int t = threadIdx.x;
  const int lane = t & 63;
  const int w = t >> 6;          // 0..3
  const int wm = w >> 1, wn = w & 1;
  const int fr = lane & 15, hi = lane >> 4;

  const int p = blockIdx.x;
  const int l = (p & 7) * 240 + (p >> 3);
  const bool isQ = l >= 1536;
  int m0, n0;
  if (!isQ) { m0 = (l / 12) * 128; n0 = 768 + (l % 12) * 128; }
  else      { const int l2 = l - 1536; m0 = (l2 / 6) * 128; n0 = (l2 % 6) * 128; }
  const unsigned short* Asel = isQ ? Apool : A;

  f32x4 acc[4][4] = {};

  const int sr8 = lane >> 3;
  const int sx8 = ((lane & 7) ^ sr8) * 8;
  const int wq = __builtin_amdgcn_readfirstlane(w);
  const unsigned short* aSrc = Asel + (size_t)(m0 + wq * 32 + sr8) * DD + sx8;
  const unsigned short* bSrc = Bt + (size_t)(n0 + wq * 32 + sr8) * DD + sx8;

#define GLOAD(SRC, DST)                                                        \
  __builtin_amdgcn_global_load_lds(                                           \
      (const __attribute__((address_space(1))) unsigned int*)(SRC),           \
      (__attribute__((address_space(3))) unsigned int*)(DST), 16, 0, 0)

#define STAGE(T) do {                                                          \
    char* da_ = smem + ((T) & 1) * 32768;                                      \
    char* db_ = da_ + 16384;                                                   \
    const unsigned short* as_ = aSrc + (T) * 64;                               \
    const unsigned short* bs_ = bSrc + (T) * 64;                               \
    _Pragma("unroll")                                                          \
    for (int i_ = 0; i_ < 4; ++i_) {                                           \
      GLOAD(as_ + (size_t)i_ * 8 * DD, da_ + (wq * 32 + i_ * 8) * 128);        \
      GLOAD(bs_ + (size_t)i_ * 8 * DD, db_ + (wq * 32 + i_ * 8) * 128);        \
    }                                                                          \
  } while (0)

  STAGE(0);
  STAGE(1);

  const int cb0 = (hi * 16) ^ ((fr & 7) << 4);
  const int cb1 = (64 + hi * 16) ^ ((fr & 7) << 4);

  for (int kt = 0; kt < NT; ++kt) {
    if (kt < NT - 1) {
      asm volatile("s_waitcnt vmcnt(8)" ::: "memory");
    } else {
      asm volatile("s_waitcnt vmcnt(0)" ::: "memory");
    }
    __builtin_amdgcn_sched_barrier(0);
    __builtin_amdgcn_s_barrier();
    __builtin_amdgcn_sched_barrier(0);

    const char* bA = smem + (kt & 1) * 32768;
    const char* bB = bA + 16384;

    bf16x8 a0[4], b0[4], a1[4], b1[4];
#pragma unroll
    for (int f = 0; f < 4; ++f) {
      a0[f] = *(const bf16x8*)(bA + (wm * 64 + f * 16 + fr) * 128 + cb0);
      b0[f] = *(const bf16x8*)(bB + (wn * 64 + f * 16 + fr) * 128 + cb0);
    }
    __builtin_amdgcn_sched_barrier(0);
#pragma unroll
    for (int f = 0; f < 4; ++f) {
      a1[f] = *(const bf16x8*)(bA + (wm * 64 + f * 16 + fr) * 128 + cb1);
      b1[f] = *(const bf16x8*)(bB + (wn * 64 + f * 16 + fr) * 128 + cb1);
    }
    asm volatile("s_waitcnt lgkmcnt(8)" ::: "memory");
    __builtin_amdgcn_sched_barrier(0);
    __builtin_amdgcn_s_setprio(1);
#pragma unroll
    for (int mf = 0; mf < 4; ++mf)
#pragma unroll
      for (int nf = 0; nf < 4; ++nf)
        acc[mf][nf] = __builtin_amdgcn_mfma_f32_16x16x32_bf16(
            a0[mf], b0[nf], acc[mf][nf], 0, 0, 0);
    __builtin_amdgcn_s_setprio(0);
    asm volatile("s_waitcnt lgkmcnt(0)" ::: "memory");
    __builtin_amdgcn_sched_barrier(0);
    __builtin_amdgcn_s_barrier();
    __builtin_amdgcn_sched_barrier(0);
    if (kt + 2 < NT) STAGE(kt + 2);
    __builtin_amdgcn_sched_barrier(0);
    __builtin_amdgcn_s_setprio(1);
#pragma unroll
    for (int mf = 0; mf < 4; ++mf)
#pragma unroll
      for (int nf = 0; nf < 4; ++nf)
        acc[mf][nf] = __builtin_amdgcn_mfma_f32_16x16x32_bf16(
            a1[mf], b1[nf], acc[mf][nf], 0, 0, 0);
    __builtin_amdgcn_s_setprio(0);
  }
#undef STAGE
#undef GLOAD

  // ---------------- fused epilogues
  if (isQ) {
#pragma unroll
    for (int mf = 0; mf < 4; ++mf) {
      const int r0 = m0 + wm * 64 + mf * 16 + hi * 4;
      const uchar4 nm = *(const uchar4*)&nmask[r0];
      const float g0 = nm.x ? 1.f : 0.f;
      const float g1 = nm.y ? 1.f : 0.f;
      const float g2 = nm.z ? 1.f : 0.f;
      const float g3 = nm.w ? 1.f : 0.f;
#pragma unroll
      for (int nf = 0; nf < 4; ++nf) {
        const int gnc = n0 + wn * 64 + nf * 16 + fr;
        const float bvs = bias[gnc];
        const f32x4 a = acc[mf][nf];
        qp[(size_t)(r0 + 0) * 768 + gnc] = f2bf((a[0] + bvs) * g0);
        qp[(size_t)(r0 + 1) * 768 + gnc] = f2bf((a[1] + bvs) * g1);
        qp[(size_t)(r0 + 2) * 768 + gnc] = f2bf((a[2] + bvs) * g2);
        qp[(size_t)(r0 + 3) * 768 + gnc] = f2bf((a[3] + bvs) * g3);
      }
    }
  } else if (n0 < 1536) {
#pragma unroll
    for (int nf = 0; nf < 4; ++nf) {
      const int nc = wn * 64 + nf * 16 + fr;
      const float bvs = bias[n0 + nc];
      const int gnc = n0 - 768 + nc;
#pragma unroll
      for (int mf = 0; mf < 4; ++mf) {
        const int gmr = m0 + wm * 64 + mf * 16 + hi * 4;
#pragma unroll
        for (int j = 0; j < 4; ++j)
          Kbuf[(size_t)(gmr + j) * 768 + gnc] = f2bf(acc[mf][nf][j] + bvs);
      }
    }
  } else {
    const int b = m0 >> 9;
    const int s0 = m0 & 511;
    unsigned short* lt = (unsigned short*)smem;
#pragma unroll
    for (int nf = 0; nf < 4; ++nf) {
      const int nl = wn * 64 + nf * 16 + fr;
      const float bvs = bias[n0 + nl];
#pragma unroll
      for (int mf = 0; mf < 4; ++mf) {
        const int mb = wm * 64 + mf * 16 + hi * 4;
        ushort4 pk;
        pk.x = f2bf(acc[mf][nf][0] + bvs);
        pk.y = f2bf(acc[mf][nf][1] + bvs);
        pk.z = f2bf(acc[mf][nf][2] + bvs);
        pk.w = f2bf(acc[mf][nf][3] + bvs);
        *(ushort4*)&lt[nl * 136 + mb] = pk;
      }
    }
    __syncthreads();
#pragma unroll
    for (int i = 0; i < 8; ++i) {
      const int row = i * 16 + (t >> 4);
      const int ch = t & 15;
      const u16x8 v = *(const u16x8*)&lt[row * 136 + ch * 8];
      const int n = n0 - 1536 + row;
      const int h2 = n >> 6, d2 = n & 63;
      *(u16x8*)(vT + ((size_t)((b * HH + h2) * HDIM + d2)) * 512 + s0 + ch * 8) = v;
    }
  }
}

// ---------------------------------------------------------------- attention
// slopes pre-scaled by log2(e)
__constant__ float c_slopes2[12] = {
    0.72134752f, 0.36067376f, 0.18033688f, 0.09016844f,
    0.04508422f, 0.02254211f, 0.011271055f, 0.0056355275f,
    1.02013945f, 0.51006972f, 0.25503486f, 0.12751743f};

// 8-wave block; block covers HALF the q-rows of one (b,h): wave w owns
// 16 q-rows (1 m-frag). 768 blocks x 8 waves, ~110 VGPR -> 4 waves/SIMD.
// K/V dbuf shared (2 gloads/wave/tile, steady vmcnt(2)), per-wave P 2 KiB.
// LDS: kt dbuf 0..16K, vt 16..32K, P 32K + w*2K, kb @49152. Total 51200.
__global__ __launch_bounds__(512, 4) void attn_mfma(
    const unsigned short* __restrict__ qp,    // [B][OL][768] bf16
    const unsigned short* __restrict__ Kb,    // [B*S][768] bf16
    const unsigned short* __restrict__ vT,    // [B][H][64][512] bf16
    const float* __restrict__ kbias,          // [B][S], pre-scaled log2e
    const unsigned char* __restrict__ nmask,  // [B][OL]
    float* __restrict__ out) {                // [B][OL][768]
  __shared__ __align__(16) char smem[51200];
  const int t = threadIdx.x;
  const int lane = t & 63;
  const int w = t >> 6;
  const int wq = __builtin_amdgcn_readfirstlane(w);
  const int fr = lane & 15, hi = lane >> 4;

  const int p = blockIdx.x;
  const int l = (p & 7) * 96 + (p >> 3);
  const int qb = l & 1;
  const int bh = l >> 1;
  const int h = bh % HH, b = bh / HH;
  const int q0 = qb * 128 + wq * 16;    // this wave's 16 q-rows

  char* ptb = smem + 32768 + wq * 2048;
  float* kbl = (float*)(smem + 49152);

  const int srow = lane >> 3;
  const int scol = ((lane & 7) ^ srow) * 8;

#define GLOAD(SRC, DST)                                                        \
  __builtin_amdgcn_global_load_lds(                                           \
      (const __attribute__((address_space(1))) unsigned int*)(SRC),           \
      (__attribute__((address_space(3))) unsigned int*)(DST), 16, 0, 0)

  // kbias -> LDS (wave 0; oldest in ledger, drained by first vmcnt(2))
  if (wq == 0) {
    GLOAD(kbias + b * SS + lane * 4, smem + 49152);
    GLOAD(kbias + b * SS + 256 + lane * 4, smem + 50176);
  }

  // Q fragment: row = q0+fr, k(d) = ks*32 + hi*8
  bf16x8 qf[2];
#pragma unroll
  for (int ks = 0; ks < 2; ++ks)
    qf[ks] = *(const bf16x8*)(qp + (size_t)(b * OL + q0 + fr) * DD +
                              h * HDIM + ks * 32 + hi * 8);

  int nmv = (int)nmask[b * OL + q0 + (lane & 15)];
  int qmbits = 0;
#pragma unroll
  for (int j = 0; j < 4; ++j)
    if (__shfl(nmv, hi * 4 + j, 64)) qmbits |= 1 << j;

  const float slope2 = c_slopes2[h];
  f32x4 oacc[4] = {};
  float lpart[4] = {};

  // wave w stages K rows [w*8, w*8+8) and V rows [w*8, w*8+8): 2 gloads
#define STAGE(TILE, BUF) do {                                                  \
    char* kd_ = smem + (BUF) * 8192 + wq * 1024;                               \
    char* vd_ = smem + 16384 + (BUF) * 8192 + wq * 1024;                       \
    const unsigned short* ks_ =                                                \
        Kb + (size_t)(b * SS + (TILE) * 64 + wq * 8 + srow) * 768 + h * HDIM + scol; \
    const unsigned short* vs_ =                                                \
        vT + (size_t)((b * HH + h) * HDIM + wq * 8 + srow) * SS + (TILE) * 64 + scol; \
    GLOAD(ks_, kd_);                                                           \
    GLOAD(vs_, vd_);                                                           \
  } while (0)

  __builtin_amdgcn_sched_barrier(0);
  STAGE(0, 0);
  STAGE(1, 1);
  __builtin_amdgcn_sched_barrier(0);

  for (int tile = 0; tile < 8; ++tile) {
    const int cur = tile & 1;
    const int key0 = tile * 64;
    if (tile < 7) {
      asm volatile("s_waitcnt vmcnt(2)" ::: "memory");
    } else {
      asm volatile("s_waitcnt vmcnt(0)" ::: "memory");
    }
    __builtin_amdgcn_sched_barrier(0);
    __builtin_amdgcn_s_barrier();          // all waves' tile data landed
    __builtin_amdgcn_sched_barrier(0);

    char* ktb = smem + cur * 8192;
    char* vtb = smem + 16384 + cur * 8192;

    // ---- QK^T (1 m-frag x 4 n-frags x 2 ks)
    f32x4 sacc[4] = {};
#pragma unroll
    for (int ks = 0; ks < 2; ++ks) {
      bf16x8 kf[4];
#pragma unroll
      for (int n = 0; n < 4; ++n) {
        const int by = ((n * 16 + fr) * 128 + (ks * 64 + hi * 16)) ^ ((fr & 7) << 4);
        kf[n] = *(const bf16x8*)(ktb + by);
      }
#pragma unroll
      for (int n = 0; n < 4; ++n)
        sacc[n] = __builtin_amdgcn_mfma_f32_16x16x32_bf16(qf[ks], kf[n], sacc[n], 0, 0, 0);
    }

    // ---- fixed-max log2-domain softmax; P -> LDS (bf16)
    float kbv[4], keyfv[4];
#pragma unroll
    for (int n = 0; n < 4; ++n) {
      kbv[n] = kbl[key0 + n * 16 + fr];
      keyfv[n] = (float)(key0 + n * 16 + fr);
    }
#pragma unroll
    for (int j = 0; j < 4; ++j) {
      const bool qm = (qmbits >> j) & 1;
      const float qvf = (float)(q0 + hi * 4 + j);
      float lp = lpart[j];
#pragma unroll
      for (int n = 0; n < 4; ++n) {
        const float biasv = qm ? kbv[n] : 0.f;
        const float rel = fabsf(keyfv[n] - qvf);
        float tv = fmaf(sacc[n][j], 0.18033688011f, biasv);
        tv = fmaf(rel, -slope2, tv);
        float pe;
        asm("v_exp_f32 %0, %1" : "=v"(pe) : "v"(tv));
        lp += pe;
        const int by = ((hi * 4 + j) * 128 + (n * 16 + fr) * 2) ^
                       (((hi * 4 + j) & 7) << 4);
        *(unsigned short*)(ptb + by) = f2bf(pe);
      }
      lpart[j] = lp;
    }
    asm volatile("s_waitcnt lgkmcnt(0)" ::: "memory");
    __builtin_amdgcn_sched_barrier(0);

    // ---- PV
#pragma unroll
    for (int ks = 0; ks < 2; ++ks) {
      bf16x8 pf, vf[4];
      {
        const int by = (fr * 128 + (ks * 64 + hi * 16)) ^ ((fr & 7) << 4);
        pf = *(const bf16x8*)(ptb + by);
      }
#pragma unroll
      for (int nd = 0; nd < 4; ++nd) {
        const int by = ((nd * 16 + fr) * 128 + (ks * 64 + hi * 16)) ^ ((fr & 7) << 4);
        vf[nd] = *(const bf16x8*)(vtb + by);
      }
#pragma unroll
      for (int nd = 0; nd < 4; ++nd)
        oacc[nd] = __builtin_amdgcn_mfma_f32_16x16x32_bf16(pf, vf[nd], oacc[nd], 0, 0, 0);
    }

    __builtin_amdgcn_sched_barrier(0);
    __builtin_amdgcn_s_barrier();          // all waves done reading buf `cur`
    __builtin_amdgcn_sched_barrier(0);
    if (tile + 2 < 8) STAGE(tile + 2, cur);
  }
#undef STAGE
#undef GLOAD

  // ---- epilogue: reduce l, normalize, transpose via per-wave LDS tile
  float* ot = (float*)(smem + wq * 4352);   // 16 x 68 f32
#pragma unroll
  for (int j = 0; j < 4; ++j) {
    float lv = lpart[j];
    lv += __shfl_xor(lv, 1, 64);
    lv += __shfl_xor(lv, 2, 64);
    lv += __shfl_xor(lv, 4, 64);
    lv += __shfl_xor(lv, 8, 64);
    const float rl = 1.f / lv;
    const int row = hi * 4 + j;
#pragma unroll
    for (int nd = 0; nd < 4; ++nd)
      ot[row * 68 + nd * 16 + fr] = oacc[nd][j] * rl;
  }
  asm volatile("s_waitcnt lgkmcnt(0)" ::: "memory");
  __builtin_amdgcn_sched_barrier(0);
#pragma unroll
  for (int i = 0; i < 4; ++i) {
    const int idx = i * 64 + lane;       // float4 index, 256 per wave
    const int row = idx >> 4, c4 = idx & 15;
    const float4 v = *(const float4*)&ot[row * 68 + c4 * 4];
    *(float4*)(out + (size_t)(b * OL + q0 + row) * DD + h * HDIM + c4 * 4) = v;
  }
}

// ---------------------------------------------------------------- launch
extern "C" void kernel_launch(void* const* d_in, const int* in_sizes, int n_in,
                              void* d_out, int out_size, void* d_ws, size_t ws_size,
                              hipStream_t stream) {
  const float* hidden = (const float*)d_in[0];
  const void* maskraw = d_in[1];
  const float* W = (const float*)d_in[2];
  const float* bias = (const float*)d_in[3];
  float* out = (float*)d_out;

  char* ws = (char*)d_ws;
  unsigned short* Abf   = (unsigned short*)(ws);                 // 25,165,824 B
  unsigned short* Btb   = (unsigned short*)(ws + 25165824);      //  3,538,944 B
  unsigned short* Kbuf  = (unsigned short*)(ws + 28704768);      // 25,165,824 B
  unsigned short* vT    = (unsigned short*)(ws + 53870592);      // 25,165,824 B
  unsigned short* qp    = (unsigned short*)(ws + 79036416);      // 12,582,912 B
  float* kbias          = (float*)(ws + 91619328);               //     65,536 B
  float* invn           = (float*)(ws + 91684864);               //     32,768 B
  unsigned char* nmask  = (unsigned char*)(ws + 91717632);       //      8,192 B
  unsigned short* Apool = (unsigned short*)(ws + 91725824);      // 12,582,912 B

  float* out_nm = out + (size_t)BB * OL * DD;  // new_mask part of d_out

  prep_all<<<7936, 256, 0, stream>>>(hidden, maskraw, W, Btb, Abf, Apool,
                                     kbias, invn, nmask, out_nm);
  gemm_qkv<<<1920, 256, 0, stream>>>(Abf, Apool, Btb, bias, Kbuf, qp, vT, nmask);
  attn_mfma<<<768, 512, 0, stream>>>(qp, Kbuf, vT, kbias, nmask, out);
}